// Round 23
// baseline (258.863 us; speedup 1.0000x reference)
//
#include <hip/hip_runtime.h>
#include <math.h>

// ---------------------------------------------------------------------------
// temporalGNN.  R15:
//  - bf16 intermediate node buffers (buf0/bufA): halves ~230MB stream traffic
//  - dispatches 12 -> 9: bcnt-zero folded into brow_sorted; bucket offset scan
//    folded into bucket_build; pool fused into head.
//  - keep: fused 3-ch gather (4-edge unroll), fp8 e4m3 interleaved tables,
//    padded-bucket CSR build, conflict-free GEMMs.
// ---------------------------------------------------------------------------

#define TT 3
#define CHUNK 2048
#define BCAP 16384

typedef __attribute__((ext_vector_type(2))) float floatx2;

__device__ __forceinline__ float sigmoidf_(float x) { return 1.f / (1.f + expf(-x)); }
__device__ __forceinline__ float bf2f(unsigned short u) {
    return __uint_as_float((unsigned)u << 16);
}
__device__ __forceinline__ unsigned short f2bf(float f) {
    unsigned u = __float_as_uint(f);
    u += 0x7FFFu + ((u >> 16) & 1u);          // RNE
    return (unsigned short)(u >> 16);
}

// ---- batch ranges from sorted batch vector (+ zero bcnt) ------------------
__global__ void brow_sorted(const int* __restrict__ batch, int* __restrict__ brow,
                            int* __restrict__ bcnt, int N, int B) {
    if (blockIdx.x == 0) bcnt[threadIdx.x] = 0;
    int n = blockIdx.x * 256 + threadIdx.x;
    if (n >= N) return;
    int b = batch[n];
    if (n == 0) {
        for (int q = 0; q <= b; ++q) brow[q] = 0;
    } else {
        int pb = batch[n - 1];
        for (int q = pb + 1; q <= b; ++q) brow[q] = n;
    }
    if (n == N - 1) {
        for (int q = b + 1; q <= B; ++q) brow[q] = N;
    }
}

// ---- stage: packed (src | local_dst<<24) into PADDED buckets --------------
__global__ void stage_direct(const int* __restrict__ src, const int* __restrict__ dst,
                             int* __restrict__ bcnt, unsigned* __restrict__ stg, int E) {
    __shared__ int hcnt[256], hbase[256], hcur[256];
    hcnt[threadIdx.x] = 0;
    __syncthreads();
    int base = blockIdx.x * CHUNK;
    for (int i = threadIdx.x; i < CHUNK; i += 256) {
        int e = base + i;
        if (e < E) atomicAdd(&hcnt[dst[e] >> 8], 1);
    }
    __syncthreads();
    int c = hcnt[threadIdx.x];
    if (c) hbase[threadIdx.x] = atomicAdd(&bcnt[threadIdx.x], c);
    hcur[threadIdx.x] = 0;
    __syncthreads();
    for (int i = threadIdx.x; i < CHUNK; i += 256) {
        int e = base + i;
        if (e < E) {
            int d = dst[e];
            int b = d >> 8;
            int r = atomicAdd(&hcur[b], 1);
            stg[(long)b * BCAP + hbase[b] + r] =
                (unsigned)src[e] | ((unsigned)(d & 255) << 24);
        }
    }
}

// ---- bucket build: bcnt scan + per-node count + rowptr/dinv + csrc --------
__global__ void bucket_build(const unsigned* __restrict__ stg, const int* __restrict__ bcnt,
                             int* __restrict__ rowptr, float* __restrict__ dinv,
                             int* __restrict__ csrc, int nb, int N, int E) {
    const int b = blockIdx.x;
    const int n0 = b << 8;
    __shared__ int cnt[256];
    __shared__ int pfx[256];
    __shared__ int boffb_sh;
    // bucket offset: exclusive scan of bcnt up to b (each block does its own)
    int bv = (threadIdx.x < nb) ? bcnt[threadIdx.x] : 0;
    pfx[threadIdx.x] = bv;
    __syncthreads();
    for (int off = 1; off < 256; off <<= 1) {
        int t = (threadIdx.x >= off) ? pfx[threadIdx.x - off] : 0;
        __syncthreads();
        pfx[threadIdx.x] += t;
        __syncthreads();
    }
    if (threadIdx.x == b) boffb_sh = pfx[threadIdx.x] - bv;
    cnt[threadIdx.x] = 0;
    __syncthreads();
    const int boffb = boffb_sh;

    const long s = (long)b * BCAP;
    const long e = s + bcnt[b];
    for (long p = s + threadIdx.x; p < e; p += 256)
        atomicAdd(&cnt[stg[p] >> 24], 1);
    __syncthreads();
    int v = cnt[threadIdx.x];
    pfx[threadIdx.x] = v;
    __syncthreads();
    for (int off = 1; off < 256; off <<= 1) {
        int t = (threadIdx.x >= off) ? pfx[threadIdx.x - off] : 0;
        __syncthreads();
        pfx[threadIdx.x] += t;
        __syncthreads();
    }
    int rowbase = boffb + pfx[threadIdx.x] - v;       // global exclusive
    int n = n0 + threadIdx.x;
    if (n < N) {
        rowptr[n] = rowbase;
        dinv[n] = rsqrtf((float)v + 2.0f);
    }
    if (b == 0 && threadIdx.x == 0) rowptr[N] = E;
    cnt[threadIdx.x] = rowbase;                       // reuse as cursor
    __syncthreads();
    for (long p = s + threadIdx.x; p < e; p += 256) {
        unsigned u = stg[p];
        int dl = u >> 24;
        int r = atomicAdd(&cnt[dl], 1);
        csrc[r] = (int)(u & 0xFFFFFFu);
    }
}

// ---- lin GEMM: fp32 x-slice @ W + b -> bf16 C -----------------------------
__global__ __launch_bounds__(256) void gemm_lin(
    const float* __restrict__ x, const float* __restrict__ W,
    const float* __restrict__ bias, unsigned short* __restrict__ C,
    long cStride, int nrows) {
    __shared__ float AT[64][68];
    __shared__ float Ws[64][68];
    const int t = threadIdx.x;
    const int r0 = blockIdx.x * 64;

    #pragma unroll
    for (int i = 0; i < 4; ++i) {
        int idx = t + i * 256;
        int k = idx >> 4, c4 = idx & 15;
        *(float4*)&Ws[k][c4 * 4] = *(const float4*)(W + k * 64 + c4 * 4);
    }
    #pragma unroll
    for (int i = 0; i < 4; ++i) {
        int idx = t + i * 256;
        int row = idx >> 4, c4 = idx & 15;
        int gr = r0 + row;
        float4 a = make_float4(0.f, 0.f, 0.f, 0.f);
        if (gr < nrows)
            a = *(const float4*)(x + (long)gr * 192 + blockIdx.y * 64 + c4 * 4);
        AT[c4 * 4 + 0][row] = a.x;
        AT[c4 * 4 + 1][row] = a.y;
        AT[c4 * 4 + 2][row] = a.z;
        AT[c4 * 4 + 3][row] = a.w;
    }
    __syncthreads();

    const int rowg = t >> 4, colg = t & 15;
    float acc[4][4] = {};
    #pragma unroll 8
    for (int k = 0; k < 64; ++k) {
        float4 av = *(const float4*)&AT[k][rowg * 4];
        float4 wv = *(const float4*)&Ws[k][colg * 4];
        #pragma unroll
        for (int i = 0; i < 4; ++i) {
            acc[i][0] = fmaf(((const float*)&av)[i], wv.x, acc[i][0]);
            acc[i][1] = fmaf(((const float*)&av)[i], wv.y, acc[i][1]);
            acc[i][2] = fmaf(((const float*)&av)[i], wv.z, acc[i][2]);
            acc[i][3] = fmaf(((const float*)&av)[i], wv.w, acc[i][3]);
        }
    }
    float b0 = bias[colg * 4 + 0], b1 = bias[colg * 4 + 1];
    float b2 = bias[colg * 4 + 2], b3 = bias[colg * 4 + 3];
    unsigned short* Cb = C + (long)blockIdx.y * cStride;
    #pragma unroll
    for (int i = 0; i < 4; ++i) {
        int gr = r0 + rowg * 4 + i;
        if (gr < nrows) {
            ushort4 o;
            o.x = f2bf(acc[i][0] + b0); o.y = f2bf(acc[i][1] + b1);
            o.z = f2bf(acc[i][2] + b2); o.w = f2bf(acc[i][3] + b3);
            *(ushort4*)(Cb + (long)gr * 64 + colg * 4) = o;
        }
    }
}

// ---- conv GEMM: bf16 A @ W -> fp8 interleaved table -----------------------
__global__ __launch_bounds__(256) void gemm_t8(
    const unsigned short* __restrict__ A, long aStride, const float* __restrict__ W,
    unsigned* __restrict__ T8, const float* __restrict__ dinvp, int nrows) {
    __shared__ float AT[64][68];
    __shared__ float Ws[64][68];
    const int t = threadIdx.x;
    const unsigned short* Ab = A + (long)blockIdx.y * aStride;
    const int r0 = blockIdx.x * 64;

    #pragma unroll
    for (int i = 0; i < 4; ++i) {
        int idx = t + i * 256;
        int k = idx >> 4, c4 = idx & 15;
        *(float4*)&Ws[k][c4 * 4] = *(const float4*)(W + k * 64 + c4 * 4);
    }
    #pragma unroll
    for (int i = 0; i < 4; ++i) {
        int idx = t + i * 256;
        int row = idx >> 4, c4 = idx & 15;
        int gr = r0 + row;
        ushort4 a = make_ushort4(0, 0, 0, 0);
        if (gr < nrows) a = *(const ushort4*)(Ab + (long)gr * 64 + c4 * 4);
        AT[c4 * 4 + 0][row] = bf2f(a.x);
        AT[c4 * 4 + 1][row] = bf2f(a.y);
        AT[c4 * 4 + 2][row] = bf2f(a.z);
        AT[c4 * 4 + 3][row] = bf2f(a.w);
    }
    __syncthreads();

    const int rowg = t >> 4, colg = t & 15;
    float acc[4][4] = {};
    #pragma unroll 8
    for (int k = 0; k < 64; ++k) {
        float4 av = *(const float4*)&AT[k][rowg * 4];
        float4 wv = *(const float4*)&Ws[k][colg * 4];
        #pragma unroll
        for (int i = 0; i < 4; ++i) {
            acc[i][0] = fmaf(((const float*)&av)[i], wv.x, acc[i][0]);
            acc[i][1] = fmaf(((const float*)&av)[i], wv.y, acc[i][1]);
            acc[i][2] = fmaf(((const float*)&av)[i], wv.z, acc[i][2]);
            acc[i][3] = fmaf(((const float*)&av)[i], wv.w, acc[i][3]);
        }
    }
    #pragma unroll
    for (int i = 0; i < 4; ++i) {
        int gr = r0 + rowg * 4 + i;
        if (gr >= nrows) continue;
        float sc = dinvp[gr];
        int r = 0;
        r = __builtin_amdgcn_cvt_pk_fp8_f32(acc[i][0] * sc, acc[i][1] * sc, r, false);
        r = __builtin_amdgcn_cvt_pk_fp8_f32(acc[i][2] * sc, acc[i][3] * sc, r, true);
        T8[(long)gr * 48 + blockIdx.y * 16 + colg] = (unsigned)r;
    }
}

// ---- fused 3-channel GCN gather, 4-edge unroll, bf16 prev/out -------------
#define EDGE3(uu)                                                        \
    {                                                                    \
        floatx2 lo = __builtin_amdgcn_cvt_pk_f32_fp8(uu, false);         \
        floatx2 hi = __builtin_amdgcn_cvt_pk_f32_fp8(uu, true);          \
        a0[ch] += lo.x; a1[ch] += lo.y; a2[ch] += hi.x; a3[ch] += hi.y;  \
    }

template <bool RELU>
__global__ __launch_bounds__(256) void gcn_gather3_f8(
    const int* __restrict__ rowptr, const int* __restrict__ csrc,
    const float* __restrict__ dinv, const unsigned* __restrict__ tc,
    const float* __restrict__ bias, const unsigned short* __restrict__ prev, long chS,
    unsigned short* __restrict__ outp, int N) {
    long gid = ((long)blockIdx.x * 256 + threadIdx.x) >> 4;
    int n = (int)gid;
    if (n >= N) return;
    const int jj = threadIdx.x & 15;

    const int end = rowptr[n + 1];
    const float din = dinv[n];
    float a0[TT] = {}, a1[TT] = {}, a2[TT] = {}, a3[TT] = {};
    int p = rowptr[n];
    for (; p + 3 < end; p += 4) {          // 4 edges x 3 ch = 12 loads in flight
        long r0 = (long)csrc[p]     * 48 + jj;
        long r1 = (long)csrc[p + 1] * 48 + jj;
        long r2 = (long)csrc[p + 2] * 48 + jj;
        long r3 = (long)csrc[p + 3] * 48 + jj;
        #pragma unroll
        for (int ch = 0; ch < TT; ++ch) {
            unsigned u0 = tc[r0 + ch * 16];
            unsigned u1 = tc[r1 + ch * 16];
            unsigned u2 = tc[r2 + ch * 16];
            unsigned u3 = tc[r3 + ch * 16];
            EDGE3(u0) EDGE3(u1) EDGE3(u2) EDGE3(u3)
        }
    }
    for (; p < end; ++p) {
        long r = (long)csrc[p] * 48 + jj;
        #pragma unroll
        for (int ch = 0; ch < TT; ++ch) {
            unsigned u = tc[r + ch * 16];
            EDGE3(u)
        }
    }
    float4 bv = *(const float4*)(bias + 4 * jj);
    long nrow = (long)n * 48 + jj;
    long off = (long)n * 64 + 4 * jj;
    #pragma unroll
    for (int ch = 0; ch < TT; ++ch) {
        unsigned us = tc[nrow + ch * 16];
        floatx2 slo = __builtin_amdgcn_cvt_pk_f32_fp8(us, false);
        floatx2 shi = __builtin_amdgcn_cvt_pk_f32_fp8(us, true);
        float v0 = (a0[ch] + 2.f * slo.x) * din + bv.x;
        float v1 = (a1[ch] + 2.f * slo.y) * din + bv.y;
        float v2 = (a2[ch] + 2.f * shi.x) * din + bv.z;
        float v3 = (a3[ch] + 2.f * shi.y) * din + bv.w;
        if (RELU) {
            v0 = fmaxf(v0, 0.f); v1 = fmaxf(v1, 0.f);
            v2 = fmaxf(v2, 0.f); v3 = fmaxf(v3, 0.f);
        }
        ushort4 pv = *(const ushort4*)(prev + ch * chS + off);
        ushort4 o;
        o.x = f2bf(v0 + bf2f(pv.x));
        o.y = f2bf(v1 + bf2f(pv.y));
        o.z = f2bf(v2 + bf2f(pv.z));
        o.w = f2bf(v3 + bf2f(pv.w));
        *(ushort4*)(outp + ch * chS + off) = o;
    }
}

// ---- head (fused pool): mean over node range, LSTM, attention, MLP --------
__global__ __launch_bounds__(256) void head_fused(
    const unsigned short* __restrict__ out2, long chS, const int* __restrict__ brow,
    const float* __restrict__ h0, const float* __restrict__ c0,
    const float* __restrict__ Wih, const float* __restrict__ Whh,
    const float* __restrict__ bih, const float* __restrict__ bhh,
    const float* __restrict__ w0W, const float* __restrict__ w0b,
    const float* __restrict__ attnW, const float* __restrict__ attnb,
    const float* __restrict__ l1W, const float* __restrict__ l1b,
    const float* __restrict__ l2W, const float* __restrict__ l2b,
    const float* __restrict__ cov, float* __restrict__ out_attn,
    float* __restrict__ out_cls) {
    const int b = blockIdx.x;
    const int t = threadIdx.x;

    __shared__ float x[TT][64];
    __shared__ float h[64], c[64];
    __shared__ float gates[256];
    __shared__ float rnn[TT][64];
    __shared__ float r[TT][64];
    __shared__ float logit[TT];
    __shared__ float a[TT];
    __shared__ float pooled[64];
    __shared__ float l1o[16];

    const int s = brow[b], e = brow[b + 1];
    float inv = 1.0f / fmaxf((float)(e - s), 1.0f);
    if (t < TT * 64) {
        int ch = t >> 6, j = t & 63;
        const unsigned short* p = out2 + (long)ch * chS + j;
        float acc = 0.f;
        for (int n = s; n < e; ++n) acc += bf2f(p[(long)n * 64]);
        x[ch][j] = acc * inv;
    }
    if (t < 64) { h[t] = h0[(long)b * 64 + t]; c[t] = c0[(long)b * 64 + t]; }
    __syncthreads();

    for (int step = 0; step < TT; ++step) {
        float g = bih[t] + bhh[t];
        const float* wi = Wih + (long)t * 64;
        const float* wh = Whh + (long)t * 64;
        #pragma unroll 8
        for (int k = 0; k < 64; ++k) g += wi[k] * x[step][k] + wh[k] * h[k];
        gates[t] = g;
        __syncthreads();
        if (t < 64) {
            float ig = sigmoidf_(gates[t]);
            float fg = sigmoidf_(gates[64 + t]);
            float gg = tanhf(gates[128 + t]);
            float og = sigmoidf_(gates[192 + t]);
            float cn = fg * c[t] + ig * gg;
            c[t] = cn;
            float hn = og * tanhf(cn);
            h[t] = hn;
            rnn[step][t] = hn;
        }
        __syncthreads();
    }

    if (t < TT * 64) {
        int tt = t / 64, j = t % 64;
        float v = w0b[j];
        const float* wr = w0W + (long)j * 64;
        #pragma unroll 8
        for (int k = 0; k < 64; ++k) v += rnn[tt][k] * wr[k];
        r[tt][j] = tanhf(v);
    }
    __syncthreads();

    if (t < TT) {
        float v = attnb[0];
        #pragma unroll 8
        for (int k = 0; k < 64; ++k) v += r[t][k] * attnW[k];
        logit[t] = v;
    }
    __syncthreads();

    if (t == 0) {
        float m = fmaxf(logit[0], fmaxf(logit[1], logit[2]));
        float e0 = expf(logit[0] - m), e1 = expf(logit[1] - m), e2 = expf(logit[2] - m);
        float sm = e0 + e1 + e2;
        a[0] = e0 / sm; a[1] = e1 / sm; a[2] = e2 / sm;
        out_attn[(long)b * TT + 0] = a[0];
        out_attn[(long)b * TT + 1] = a[1];
        out_attn[(long)b * TT + 2] = a[2];
    }
    __syncthreads();

    if (t < 64) pooled[t] = a[0] * r[0][t] + a[1] * r[1][t] + a[2] * r[2][t];
    __syncthreads();

    if (t < 8) {
        float v = l1b[t];
        const float* w = l1W + (long)t * 64;
        #pragma unroll 8
        for (int k = 0; k < 64; ++k) v += pooled[k] * w[k];
        l1o[t] = fmaxf(v, 0.f);
    } else if (t < 16) {
        l1o[t] = cov[(long)b * 8 + (t - 8)];
    }
    __syncthreads();

    if (t < 2) {
        float v = l2b[t];
        const float* w = l2W + (long)t * 16;
        #pragma unroll
        for (int k = 0; k < 16; ++k) v += l1o[k] * w[k];
        out_cls[(long)b * 2 + t] = v;
    }
}

// ---------------------------------------------------------------------------
extern "C" void kernel_launch(void* const* d_in, const int* in_sizes, int n_in,
                              void* d_out, int out_size, void* d_ws, size_t ws_size,
                              hipStream_t stream) {
    const float* x       = (const float*)d_in[0];
    const int*   eidx    = (const int*)d_in[1];
    const float* cov     = (const float*)d_in[2];
    const int*   batch   = (const int*)d_in[3];
    const float* h0      = (const float*)d_in[4];
    const float* c0      = (const float*)d_in[5];
    const float* lin_W   = (const float*)d_in[6];
    const float* lin_b   = (const float*)d_in[7];
    const float* conv1_W = (const float*)d_in[8];
    const float* conv1_b = (const float*)d_in[9];
    const float* conv2_W = (const float*)d_in[10];
    const float* conv2_b = (const float*)d_in[11];
    const float* Wih     = (const float*)d_in[12];
    const float* Whh     = (const float*)d_in[13];
    const float* bih     = (const float*)d_in[14];
    const float* bhh     = (const float*)d_in[15];
    const float* w0_W    = (const float*)d_in[16];
    const float* w0_b    = (const float*)d_in[17];
    const float* attn_W  = (const float*)d_in[18];
    const float* attn_b  = (const float*)d_in[19];
    const float* l1_W    = (const float*)d_in[20];
    const float* l1_b    = (const float*)d_in[21];
    const float* l2_W    = (const float*)d_in[22];
    const float* l2_b    = (const float*)d_in[23];

    const int N = in_sizes[3];
    const int E = in_sizes[1] / 2;
    const int B = in_sizes[2] / 8;

    const int* src = eidx;
    const int* dst = eidx + E;

    auto cdiv = [](long a, long b) { return (int)((a + b - 1) / b); };
    const int nb = cdiv(N, 256);            // buckets of 256 nodes

    // workspace
    char* w = (char*)d_ws;
    float* dinv   = (float*)w;  w += (size_t)N * 4;
    int*   rowptr = (int*)w;    w += (size_t)(N + 1) * 4;
    int*   brow   = (int*)w;    w += (size_t)(B + 1) * 4;
    int*   bcnt   = (int*)w;    w += 256 * 4;
    int*   csrc   = (int*)w;    w += (size_t)E * 4;
    unsigned* stg = (unsigned*)w; w += (size_t)nb * BCAP * 4;
    unsigned short* buf0 = (unsigned short*)w;  w += (size_t)TT * N * 64 * 2;
    unsigned short* bufA = (unsigned short*)w;  w += (size_t)TT * N * 64 * 2;
    unsigned* tb8 = (unsigned*)w;  w += (size_t)N * 48 * 4;     // interleaved fp8
    const long chS = (long)N * 64;

    float* out_attn = (float*)d_out;
    float* out_cls  = out_attn + (long)B * TT;

    // ---- CSR build (3 dispatches) ----
    brow_sorted<<<cdiv(N, 256), 256, 0, stream>>>(batch, brow, bcnt, N, B);
    stage_direct<<<cdiv(E, CHUNK), 256, 0, stream>>>(src, dst, bcnt, stg, E);
    bucket_build<<<nb, 256, 0, stream>>>(stg, bcnt, rowptr, dinv, csrc, nb, N, E);

    const int gemm_gx = cdiv(N, 64);
    const int ng_gx   = cdiv((long)N * 16, 256);

    // lin GEMM -> buf0 (bf16)
    {
        dim3 ggrid(gemm_gx, TT);
        gemm_lin<<<ggrid, 256, 0, stream>>>(x, lin_W, lin_b, buf0, chS, N);
    }
    // conv1 GEMM -> interleaved fp8 table
    {
        dim3 ggrid(gemm_gx, TT);
        gemm_t8<<<ggrid, 256, 0, stream>>>(buf0, chS, conv1_W, tb8, dinv, N);
    }
    gcn_gather3_f8<true><<<ng_gx, 256, 0, stream>>>(
        rowptr, csrc, dinv, tb8, conv1_b, buf0, chS, bufA, N);
    // conv2 GEMM -> interleaved fp8 table
    {
        dim3 ggrid(gemm_gx, TT);
        gemm_t8<<<ggrid, 256, 0, stream>>>(bufA, chS, conv2_W, tb8, dinv, N);
    }
    gcn_gather3_f8<false><<<ng_gx, 256, 0, stream>>>(
        rowptr, csrc, dinv, tb8, conv2_b, bufA, chS, buf0, N);

    head_fused<<<B, 256, 0, stream>>>(buf0, chS, brow, h0, c0, Wih, Whh, bih, bhh,
                                      w0_W, w0_b, attn_W, attn_b, l1_W, l1_b,
                                      l2_W, l2_b, cov, out_attn, out_cls);
}

// Round 24
// 217.768 us; speedup vs baseline: 1.1887x; 1.1887x over previous
//
#include <hip/hip_runtime.h>
#include <math.h>

// ---------------------------------------------------------------------------
// temporalGNN.  R16 = R15 with pool UN-fused (head_fused was 80us serial):
//  - bf16 intermediate node buffers; fp8 interleaved gather tables
//  - pool_range (grid Bx3, parallel) -> fp32 seq -> head_kernel
//  - 3-dispatch CSR build, conflict-free GEMMs, fused 3-ch gather
// ---------------------------------------------------------------------------

#define TT 3
#define CHUNK 2048
#define BCAP 16384

typedef __attribute__((ext_vector_type(2))) float floatx2;

__device__ __forceinline__ float sigmoidf_(float x) { return 1.f / (1.f + expf(-x)); }
__device__ __forceinline__ float bf2f(unsigned short u) {
    return __uint_as_float((unsigned)u << 16);
}
__device__ __forceinline__ unsigned short f2bf(float f) {
    unsigned u = __float_as_uint(f);
    u += 0x7FFFu + ((u >> 16) & 1u);          // RNE
    return (unsigned short)(u >> 16);
}

// ---- batch ranges from sorted batch vector (+ zero bcnt) ------------------
__global__ void brow_sorted(const int* __restrict__ batch, int* __restrict__ brow,
                            int* __restrict__ bcnt, int N, int B) {
    if (blockIdx.x == 0) bcnt[threadIdx.x] = 0;
    int n = blockIdx.x * 256 + threadIdx.x;
    if (n >= N) return;
    int b = batch[n];
    if (n == 0) {
        for (int q = 0; q <= b; ++q) brow[q] = 0;
    } else {
        int pb = batch[n - 1];
        for (int q = pb + 1; q <= b; ++q) brow[q] = n;
    }
    if (n == N - 1) {
        for (int q = b + 1; q <= B; ++q) brow[q] = N;
    }
}

// ---- stage: packed (src | local_dst<<24) into PADDED buckets --------------
__global__ void stage_direct(const int* __restrict__ src, const int* __restrict__ dst,
                             int* __restrict__ bcnt, unsigned* __restrict__ stg, int E) {
    __shared__ int hcnt[256], hbase[256], hcur[256];
    hcnt[threadIdx.x] = 0;
    __syncthreads();
    int base = blockIdx.x * CHUNK;
    for (int i = threadIdx.x; i < CHUNK; i += 256) {
        int e = base + i;
        if (e < E) atomicAdd(&hcnt[dst[e] >> 8], 1);
    }
    __syncthreads();
    int c = hcnt[threadIdx.x];
    if (c) hbase[threadIdx.x] = atomicAdd(&bcnt[threadIdx.x], c);
    hcur[threadIdx.x] = 0;
    __syncthreads();
    for (int i = threadIdx.x; i < CHUNK; i += 256) {
        int e = base + i;
        if (e < E) {
            int d = dst[e];
            int b = d >> 8;
            int r = atomicAdd(&hcur[b], 1);
            stg[(long)b * BCAP + hbase[b] + r] =
                (unsigned)src[e] | ((unsigned)(d & 255) << 24);
        }
    }
}

// ---- bucket build: bcnt scan + per-node count + rowptr/dinv + csrc --------
__global__ void bucket_build(const unsigned* __restrict__ stg, const int* __restrict__ bcnt,
                             int* __restrict__ rowptr, float* __restrict__ dinv,
                             int* __restrict__ csrc, int nb, int N, int E) {
    const int b = blockIdx.x;
    const int n0 = b << 8;
    __shared__ int cnt[256];
    __shared__ int pfx[256];
    __shared__ int boffb_sh;
    int bv = (threadIdx.x < nb) ? bcnt[threadIdx.x] : 0;
    pfx[threadIdx.x] = bv;
    __syncthreads();
    for (int off = 1; off < 256; off <<= 1) {
        int t = (threadIdx.x >= off) ? pfx[threadIdx.x - off] : 0;
        __syncthreads();
        pfx[threadIdx.x] += t;
        __syncthreads();
    }
    if (threadIdx.x == b) boffb_sh = pfx[threadIdx.x] - bv;
    cnt[threadIdx.x] = 0;
    __syncthreads();
    const int boffb = boffb_sh;

    const long s = (long)b * BCAP;
    const long e = s + bcnt[b];
    for (long p = s + threadIdx.x; p < e; p += 256)
        atomicAdd(&cnt[stg[p] >> 24], 1);
    __syncthreads();
    int v = cnt[threadIdx.x];
    pfx[threadIdx.x] = v;
    __syncthreads();
    for (int off = 1; off < 256; off <<= 1) {
        int t = (threadIdx.x >= off) ? pfx[threadIdx.x - off] : 0;
        __syncthreads();
        pfx[threadIdx.x] += t;
        __syncthreads();
    }
    int rowbase = boffb + pfx[threadIdx.x] - v;       // global exclusive
    int n = n0 + threadIdx.x;
    if (n < N) {
        rowptr[n] = rowbase;
        dinv[n] = rsqrtf((float)v + 2.0f);
    }
    if (b == 0 && threadIdx.x == 0) rowptr[N] = E;
    cnt[threadIdx.x] = rowbase;                       // reuse as cursor
    __syncthreads();
    for (long p = s + threadIdx.x; p < e; p += 256) {
        unsigned u = stg[p];
        int dl = u >> 24;
        int r = atomicAdd(&cnt[dl], 1);
        csrc[r] = (int)(u & 0xFFFFFFu);
    }
}

// ---- lin GEMM: fp32 x-slice @ W + b -> bf16 C -----------------------------
__global__ __launch_bounds__(256) void gemm_lin(
    const float* __restrict__ x, const float* __restrict__ W,
    const float* __restrict__ bias, unsigned short* __restrict__ C,
    long cStride, int nrows) {
    __shared__ float AT[64][68];
    __shared__ float Ws[64][68];
    const int t = threadIdx.x;
    const int r0 = blockIdx.x * 64;

    #pragma unroll
    for (int i = 0; i < 4; ++i) {
        int idx = t + i * 256;
        int k = idx >> 4, c4 = idx & 15;
        *(float4*)&Ws[k][c4 * 4] = *(const float4*)(W + k * 64 + c4 * 4);
    }
    #pragma unroll
    for (int i = 0; i < 4; ++i) {
        int idx = t + i * 256;
        int row = idx >> 4, c4 = idx & 15;
        int gr = r0 + row;
        float4 a = make_float4(0.f, 0.f, 0.f, 0.f);
        if (gr < nrows)
            a = *(const float4*)(x + (long)gr * 192 + blockIdx.y * 64 + c4 * 4);
        AT[c4 * 4 + 0][row] = a.x;
        AT[c4 * 4 + 1][row] = a.y;
        AT[c4 * 4 + 2][row] = a.z;
        AT[c4 * 4 + 3][row] = a.w;
    }
    __syncthreads();

    const int rowg = t >> 4, colg = t & 15;
    float acc[4][4] = {};
    #pragma unroll 8
    for (int k = 0; k < 64; ++k) {
        float4 av = *(const float4*)&AT[k][rowg * 4];
        float4 wv = *(const float4*)&Ws[k][colg * 4];
        #pragma unroll
        for (int i = 0; i < 4; ++i) {
            acc[i][0] = fmaf(((const float*)&av)[i], wv.x, acc[i][0]);
            acc[i][1] = fmaf(((const float*)&av)[i], wv.y, acc[i][1]);
            acc[i][2] = fmaf(((const float*)&av)[i], wv.z, acc[i][2]);
            acc[i][3] = fmaf(((const float*)&av)[i], wv.w, acc[i][3]);
        }
    }
    float b0 = bias[colg * 4 + 0], b1 = bias[colg * 4 + 1];
    float b2 = bias[colg * 4 + 2], b3 = bias[colg * 4 + 3];
    unsigned short* Cb = C + (long)blockIdx.y * cStride;
    #pragma unroll
    for (int i = 0; i < 4; ++i) {
        int gr = r0 + rowg * 4 + i;
        if (gr < nrows) {
            ushort4 o;
            o.x = f2bf(acc[i][0] + b0); o.y = f2bf(acc[i][1] + b1);
            o.z = f2bf(acc[i][2] + b2); o.w = f2bf(acc[i][3] + b3);
            *(ushort4*)(Cb + (long)gr * 64 + colg * 4) = o;
        }
    }
}

// ---- conv GEMM: bf16 A @ W -> fp8 interleaved table -----------------------
__global__ __launch_bounds__(256) void gemm_t8(
    const unsigned short* __restrict__ A, long aStride, const float* __restrict__ W,
    unsigned* __restrict__ T8, const float* __restrict__ dinvp, int nrows) {
    __shared__ float AT[64][68];
    __shared__ float Ws[64][68];
    const int t = threadIdx.x;
    const unsigned short* Ab = A + (long)blockIdx.y * aStride;
    const int r0 = blockIdx.x * 64;

    #pragma unroll
    for (int i = 0; i < 4; ++i) {
        int idx = t + i * 256;
        int k = idx >> 4, c4 = idx & 15;
        *(float4*)&Ws[k][c4 * 4] = *(const float4*)(W + k * 64 + c4 * 4);
    }
    #pragma unroll
    for (int i = 0; i < 4; ++i) {
        int idx = t + i * 256;
        int row = idx >> 4, c4 = idx & 15;
        int gr = r0 + row;
        ushort4 a = make_ushort4(0, 0, 0, 0);
        if (gr < nrows) a = *(const ushort4*)(Ab + (long)gr * 64 + c4 * 4);
        AT[c4 * 4 + 0][row] = bf2f(a.x);
        AT[c4 * 4 + 1][row] = bf2f(a.y);
        AT[c4 * 4 + 2][row] = bf2f(a.z);
        AT[c4 * 4 + 3][row] = bf2f(a.w);
    }
    __syncthreads();

    const int rowg = t >> 4, colg = t & 15;
    float acc[4][4] = {};
    #pragma unroll 8
    for (int k = 0; k < 64; ++k) {
        float4 av = *(const float4*)&AT[k][rowg * 4];
        float4 wv = *(const float4*)&Ws[k][colg * 4];
        #pragma unroll
        for (int i = 0; i < 4; ++i) {
            acc[i][0] = fmaf(((const float*)&av)[i], wv.x, acc[i][0]);
            acc[i][1] = fmaf(((const float*)&av)[i], wv.y, acc[i][1]);
            acc[i][2] = fmaf(((const float*)&av)[i], wv.z, acc[i][2]);
            acc[i][3] = fmaf(((const float*)&av)[i], wv.w, acc[i][3]);
        }
    }
    #pragma unroll
    for (int i = 0; i < 4; ++i) {
        int gr = r0 + rowg * 4 + i;
        if (gr >= nrows) continue;
        float sc = dinvp[gr];
        int r = 0;
        r = __builtin_amdgcn_cvt_pk_fp8_f32(acc[i][0] * sc, acc[i][1] * sc, r, false);
        r = __builtin_amdgcn_cvt_pk_fp8_f32(acc[i][2] * sc, acc[i][3] * sc, r, true);
        T8[(long)gr * 48 + blockIdx.y * 16 + colg] = (unsigned)r;
    }
}

// ---- fused 3-channel GCN gather, 4-edge unroll, bf16 prev/out -------------
#define EDGE3(uu)                                                        \
    {                                                                    \
        floatx2 lo = __builtin_amdgcn_cvt_pk_f32_fp8(uu, false);         \
        floatx2 hi = __builtin_amdgcn_cvt_pk_f32_fp8(uu, true);          \
        a0[ch] += lo.x; a1[ch] += lo.y; a2[ch] += hi.x; a3[ch] += hi.y;  \
    }

template <bool RELU>
__global__ __launch_bounds__(256) void gcn_gather3_f8(
    const int* __restrict__ rowptr, const int* __restrict__ csrc,
    const float* __restrict__ dinv, const unsigned* __restrict__ tc,
    const float* __restrict__ bias, const unsigned short* __restrict__ prev, long chS,
    unsigned short* __restrict__ outp, int N) {
    long gid = ((long)blockIdx.x * 256 + threadIdx.x) >> 4;
    int n = (int)gid;
    if (n >= N) return;
    const int jj = threadIdx.x & 15;

    const int end = rowptr[n + 1];
    const float din = dinv[n];
    float a0[TT] = {}, a1[TT] = {}, a2[TT] = {}, a3[TT] = {};
    int p = rowptr[n];
    for (; p + 3 < end; p += 4) {          // 4 edges x 3 ch = 12 loads in flight
        long r0 = (long)csrc[p]     * 48 + jj;
        long r1 = (long)csrc[p + 1] * 48 + jj;
        long r2 = (long)csrc[p + 2] * 48 + jj;
        long r3 = (long)csrc[p + 3] * 48 + jj;
        #pragma unroll
        for (int ch = 0; ch < TT; ++ch) {
            unsigned u0 = tc[r0 + ch * 16];
            unsigned u1 = tc[r1 + ch * 16];
            unsigned u2 = tc[r2 + ch * 16];
            unsigned u3 = tc[r3 + ch * 16];
            EDGE3(u0) EDGE3(u1) EDGE3(u2) EDGE3(u3)
        }
    }
    for (; p < end; ++p) {
        long r = (long)csrc[p] * 48 + jj;
        #pragma unroll
        for (int ch = 0; ch < TT; ++ch) {
            unsigned u = tc[r + ch * 16];
            EDGE3(u)
        }
    }
    float4 bv = *(const float4*)(bias + 4 * jj);
    long nrow = (long)n * 48 + jj;
    long off = (long)n * 64 + 4 * jj;
    #pragma unroll
    for (int ch = 0; ch < TT; ++ch) {
        unsigned us = tc[nrow + ch * 16];
        floatx2 slo = __builtin_amdgcn_cvt_pk_f32_fp8(us, false);
        floatx2 shi = __builtin_amdgcn_cvt_pk_f32_fp8(us, true);
        float v0 = (a0[ch] + 2.f * slo.x) * din + bv.x;
        float v1 = (a1[ch] + 2.f * slo.y) * din + bv.y;
        float v2 = (a2[ch] + 2.f * shi.x) * din + bv.z;
        float v3 = (a3[ch] + 2.f * shi.y) * din + bv.w;
        if (RELU) {
            v0 = fmaxf(v0, 0.f); v1 = fmaxf(v1, 0.f);
            v2 = fmaxf(v2, 0.f); v3 = fmaxf(v3, 0.f);
        }
        ushort4 pv = *(const ushort4*)(prev + ch * chS + off);
        ushort4 o;
        o.x = f2bf(v0 + bf2f(pv.x));
        o.y = f2bf(v1 + bf2f(pv.y));
        o.z = f2bf(v2 + bf2f(pv.z));
        o.w = f2bf(v3 + bf2f(pv.w));
        *(ushort4*)(outp + ch * chS + off) = o;
    }
}

// ---- range-based pool numerator (bf16 in, fp32 seq out, grid B x 3) -------
__global__ __launch_bounds__(256) void pool_range(
    const unsigned short* __restrict__ out2, long chStride,
    const int* __restrict__ brow, float* __restrict__ seq) {
    const int b = blockIdx.x;
    const int chan = blockIdx.y;
    const unsigned short* src = out2 + (long)chan * chStride;
    const int j = threadIdx.x & 63;
    const int w = threadIdx.x >> 6;
    __shared__ float part[4][64];
    float acc = 0.f;
    const int s = brow[b], e = brow[b + 1];
    for (int n = s + w; n < e; n += 4) acc += bf2f(src[(long)n * 64 + j]);
    part[w][j] = acc;
    __syncthreads();
    if (w == 0)
        seq[((long)b * TT + chan) * 64 + j] = part[0][j] + part[1][j] + part[2][j] + part[3][j];
}

// ---- head ----------------------------------------------------------------
__global__ __launch_bounds__(256) void head_kernel(
    const float* __restrict__ seq, const int* __restrict__ brow,
    const float* __restrict__ h0, const float* __restrict__ c0,
    const float* __restrict__ Wih, const float* __restrict__ Whh,
    const float* __restrict__ bih, const float* __restrict__ bhh,
    const float* __restrict__ w0W, const float* __restrict__ w0b,
    const float* __restrict__ attnW, const float* __restrict__ attnb,
    const float* __restrict__ l1W, const float* __restrict__ l1b,
    const float* __restrict__ l2W, const float* __restrict__ l2b,
    const float* __restrict__ cov, float* __restrict__ out_attn,
    float* __restrict__ out_cls) {
    const int b = blockIdx.x;
    const int t = threadIdx.x;

    __shared__ float x[TT][64];
    __shared__ float h[64], c[64];
    __shared__ float gates[256];
    __shared__ float rnn[TT][64];
    __shared__ float r[TT][64];
    __shared__ float logit[TT];
    __shared__ float a[TT];
    __shared__ float pooled[64];
    __shared__ float l1o[16];

    float inv = 1.0f / fmaxf((float)(brow[b + 1] - brow[b]), 1.0f);
    if (t < TT * 64) x[t / 64][t % 64] = seq[(long)b * TT * 64 + t] * inv;
    if (t < 64) { h[t] = h0[(long)b * 64 + t]; c[t] = c0[(long)b * 64 + t]; }
    __syncthreads();

    for (int step = 0; step < TT; ++step) {
        float g = bih[t] + bhh[t];
        const float* wi = Wih + (long)t * 64;
        const float* wh = Whh + (long)t * 64;
        #pragma unroll 8
        for (int k = 0; k < 64; ++k) g += wi[k] * x[step][k] + wh[k] * h[k];
        gates[t] = g;
        __syncthreads();
        if (t < 64) {
            float ig = sigmoidf_(gates[t]);
            float fg = sigmoidf_(gates[64 + t]);
            float gg = tanhf(gates[128 + t]);
            float og = sigmoidf_(gates[192 + t]);
            float cn = fg * c[t] + ig * gg;
            c[t] = cn;
            float hn = og * tanhf(cn);
            h[t] = hn;
            rnn[step][t] = hn;
        }
        __syncthreads();
    }

    if (t < TT * 64) {
        int tt = t / 64, j = t % 64;
        float v = w0b[j];
        const float* wr = w0W + (long)j * 64;
        #pragma unroll 8
        for (int k = 0; k < 64; ++k) v += rnn[tt][k] * wr[k];
        r[tt][j] = tanhf(v);
    }
    __syncthreads();

    if (t < TT) {
        float v = attnb[0];
        #pragma unroll 8
        for (int k = 0; k < 64; ++k) v += r[t][k] * attnW[k];
        logit[t] = v;
    }
    __syncthreads();

    if (t == 0) {
        float m = fmaxf(logit[0], fmaxf(logit[1], logit[2]));
        float e0 = expf(logit[0] - m), e1 = expf(logit[1] - m), e2 = expf(logit[2] - m);
        float s = e0 + e1 + e2;
        a[0] = e0 / s; a[1] = e1 / s; a[2] = e2 / s;
        out_attn[(long)b * TT + 0] = a[0];
        out_attn[(long)b * TT + 1] = a[1];
        out_attn[(long)b * TT + 2] = a[2];
    }
    __syncthreads();

    if (t < 64) pooled[t] = a[0] * r[0][t] + a[1] * r[1][t] + a[2] * r[2][t];
    __syncthreads();

    if (t < 8) {
        float v = l1b[t];
        const float* w = l1W + (long)t * 64;
        #pragma unroll 8
        for (int k = 0; k < 64; ++k) v += pooled[k] * w[k];
        l1o[t] = fmaxf(v, 0.f);
    } else if (t < 16) {
        l1o[t] = cov[(long)b * 8 + (t - 8)];
    }
    __syncthreads();

    if (t < 2) {
        float v = l2b[t];
        const float* w = l2W + (long)t * 16;
        #pragma unroll
        for (int k = 0; k < 16; ++k) v += l1o[k] * w[k];
        out_cls[(long)b * 2 + t] = v;
    }
}

// ---------------------------------------------------------------------------
extern "C" void kernel_launch(void* const* d_in, const int* in_sizes, int n_in,
                              void* d_out, int out_size, void* d_ws, size_t ws_size,
                              hipStream_t stream) {
    const float* x       = (const float*)d_in[0];
    const int*   eidx    = (const int*)d_in[1];
    const float* cov     = (const float*)d_in[2];
    const int*   batch   = (const int*)d_in[3];
    const float* h0      = (const float*)d_in[4];
    const float* c0      = (const float*)d_in[5];
    const float* lin_W   = (const float*)d_in[6];
    const float* lin_b   = (const float*)d_in[7];
    const float* conv1_W = (const float*)d_in[8];
    const float* conv1_b = (const float*)d_in[9];
    const float* conv2_W = (const float*)d_in[10];
    const float* conv2_b = (const float*)d_in[11];
    const float* Wih     = (const float*)d_in[12];
    const float* Whh     = (const float*)d_in[13];
    const float* bih     = (const float*)d_in[14];
    const float* bhh     = (const float*)d_in[15];
    const float* w0_W    = (const float*)d_in[16];
    const float* w0_b    = (const float*)d_in[17];
    const float* attn_W  = (const float*)d_in[18];
    const float* attn_b  = (const float*)d_in[19];
    const float* l1_W    = (const float*)d_in[20];
    const float* l1_b    = (const float*)d_in[21];
    const float* l2_W    = (const float*)d_in[22];
    const float* l2_b    = (const float*)d_in[23];

    const int N = in_sizes[3];
    const int E = in_sizes[1] / 2;
    const int B = in_sizes[2] / 8;

    const int* src = eidx;
    const int* dst = eidx + E;

    auto cdiv = [](long a, long b) { return (int)((a + b - 1) / b); };
    const int nb = cdiv(N, 256);            // buckets of 256 nodes

    // workspace
    char* w = (char*)d_ws;
    float* dinv   = (float*)w;  w += (size_t)N * 4;
    int*   rowptr = (int*)w;    w += (size_t)(N + 1) * 4;
    int*   brow   = (int*)w;    w += (size_t)(B + 1) * 4;
    int*   bcnt   = (int*)w;    w += 256 * 4;
    int*   csrc   = (int*)w;    w += (size_t)E * 4;
    unsigned* stg = (unsigned*)w; w += (size_t)nb * BCAP * 4;
    float* seq    = (float*)w;  w += (size_t)B * TT * 64 * 4;
    unsigned short* buf0 = (unsigned short*)w;  w += (size_t)TT * N * 64 * 2;
    unsigned short* bufA = (unsigned short*)w;  w += (size_t)TT * N * 64 * 2;
    unsigned* tb8 = (unsigned*)w;  w += (size_t)N * 48 * 4;     // interleaved fp8
    const long chS = (long)N * 64;

    float* out_attn = (float*)d_out;
    float* out_cls  = out_attn + (long)B * TT;

    // ---- CSR build (3 dispatches) ----
    brow_sorted<<<cdiv(N, 256), 256, 0, stream>>>(batch, brow, bcnt, N, B);
    stage_direct<<<cdiv(E, CHUNK), 256, 0, stream>>>(src, dst, bcnt, stg, E);
    bucket_build<<<nb, 256, 0, stream>>>(stg, bcnt, rowptr, dinv, csrc, nb, N, E);

    const int gemm_gx = cdiv(N, 64);
    const int ng_gx   = cdiv((long)N * 16, 256);

    // lin GEMM -> buf0 (bf16)
    {
        dim3 ggrid(gemm_gx, TT);
        gemm_lin<<<ggrid, 256, 0, stream>>>(x, lin_W, lin_b, buf0, chS, N);
    }
    // conv1 GEMM -> interleaved fp8 table
    {
        dim3 ggrid(gemm_gx, TT);
        gemm_t8<<<ggrid, 256, 0, stream>>>(buf0, chS, conv1_W, tb8, dinv, N);
    }
    gcn_gather3_f8<true><<<ng_gx, 256, 0, stream>>>(
        rowptr, csrc, dinv, tb8, conv1_b, buf0, chS, bufA, N);
    // conv2 GEMM -> interleaved fp8 table
    {
        dim3 ggrid(gemm_gx, TT);
        gemm_t8<<<ggrid, 256, 0, stream>>>(bufA, chS, conv2_W, tb8, dinv, N);
    }
    gcn_gather3_f8<false><<<ng_gx, 256, 0, stream>>>(
        rowptr, csrc, dinv, tb8, conv2_b, bufA, chS, buf0, N);

    {
        dim3 pgrid(B, TT);
        pool_range<<<pgrid, 256, 0, stream>>>(buf0, chS, brow, seq);
    }

    head_kernel<<<B, 256, 0, stream>>>(seq, brow, h0, c0, Wih, Whh, bih, bhh,
                                       w0_W, w0_b, attn_W, attn_b, l1_W, l1_b,
                                       l2_W, l2_b, cov, out_attn, out_cls);
}